// Round 1
// baseline (237.310 us; speedup 1.0000x reference)
//
#include <hip/hip_runtime.h>

// DenseLayerWithComplexNeurons: out = per-cell-type-MLP( x @ W^T + b )
// M = B*S = 8192, K = DIN = 1024, N = A*DOUT = 4096, DOUT = 1024
// T = 4 cell types, G = 256 neurons/type, A = 4, H = 8.
//
// Round 0 design: bf16 MFMA GEMM (m97 recipe: 128x128 tile, BK=64,
// global_load_lds width=16, ds_read_b128 frags, 16x16x32 bf16 MFMA),
// epilogue fused via LDS round-trip in two 64-row halves (z-buffer
// aliases the staging LDS, stride 132 floats to keep banks happy).

typedef __bf16 bf16x8 __attribute__((ext_vector_type(8)));
typedef float f32x4 __attribute__((ext_vector_type(4)));

#define BM 128
#define BN 128
#define BK 64
#define KDIM 1024
#define ZSTRIDE 132  // floats; multiple of 4 (16B-aligned rows), 132%32=4 -> 2-way max on b32 writes

__global__ __launch_bounds__(256) void cvt_bf16_kernel(
    const float* __restrict__ in, __bf16* __restrict__ out, int n8) {
    int i = blockIdx.x * 256 + threadIdx.x;
    if (i >= n8) return;
    const f32x4* p = (const f32x4*)in + 2 * (size_t)i;
    f32x4 a = p[0], b = p[1];
    bf16x8 o;
    o[0] = (__bf16)a[0]; o[1] = (__bf16)a[1]; o[2] = (__bf16)a[2]; o[3] = (__bf16)a[3];
    o[4] = (__bf16)b[0]; o[5] = (__bf16)b[1]; o[6] = (__bf16)b[2]; o[7] = (__bf16)b[3];
    ((bf16x8*)out)[i] = o;
}

union __align__(16) SmemU {
    __bf16 stg[BM * BK + BN * BK];   // A tile then B tile, row-major [row][k]
    float  z[64 * ZSTRIDE];          // one 64-row half of the z tile, [m][n] padded
};

__global__ __launch_bounds__(256) void fused_gemm_mlp_kernel(
    const __bf16* __restrict__ Ag,   // [8192][1024] bf16 (x)
    const __bf16* __restrict__ Bg,   // [4096][1024] bf16 (weight, already B^T layout)
    const float* __restrict__ bias,  // [4096]
    const float* __restrict__ cw1,   // [4][4][8]
    const float* __restrict__ cb1,   // [4][8]
    const float* __restrict__ cw2,   // [4][8]
    const float* __restrict__ cb2,   // [4]
    float* __restrict__ out)         // [8192][1024]
{
    __shared__ SmemU u;

    const int tid  = threadIdx.x;
    const int wave = tid >> 6;
    const int lane = tid & 63;
    const int wm = wave >> 1;        // wave row (0..1), 64 rows each
    const int wn = wave & 1;         // wave col (0..1), 64 cols each
    const int bn0 = blockIdx.x * BN; // n offset in [0,4096)
    const int bm0 = blockIdx.y * BM; // m offset in [0,8192)

    f32x4 acc[4][4] = {};

    // staging lane mapping: within an 8-row chunk, lane covers
    // row = chunk*8 + (lane>>3), 16B at byte-offset (lane&7)*16 in the row.
    const int arow  = lane >> 3;
    const int acol8 = (lane & 7) * 8;  // element offset

    for (int k0 = 0; k0 < KDIM; k0 += BK) {
        // ---- stage A (128x64) and B (128x64) via global_load_lds width=16 ----
#pragma unroll
        for (int c = 0; c < 4; ++c) {
            const int chunk = wave + c * 4;  // 16 chunks of 8 rows, 4 per wave
            const __bf16* ga = Ag + (size_t)(bm0 + chunk * 8 + arow) * KDIM + k0 + acol8;
            __builtin_amdgcn_global_load_lds(
                (__attribute__((address_space(1))) void*)ga,
                (__attribute__((address_space(3))) void*)&u.stg[chunk * 8 * BK],
                16, 0, 0);
            const __bf16* gb = Bg + (size_t)(bn0 + chunk * 8 + arow) * KDIM + k0 + acol8;
            __builtin_amdgcn_global_load_lds(
                (__attribute__((address_space(1))) void*)gb,
                (__attribute__((address_space(3))) void*)&u.stg[BM * BK + chunk * 8 * BK],
                16, 0, 0);
        }
        __syncthreads();  // compiler emits vmcnt(0) drain before s_barrier

        // ---- MFMA on the tile: 2 k-halves of 32 ----
#pragma unroll
        for (int kk = 0; kk < BK; kk += 32) {
            bf16x8 af[4], bfr[4];
#pragma unroll
            for (int mi = 0; mi < 4; ++mi)
                af[mi] = *(const bf16x8*)&u.stg[(wm * 64 + mi * 16 + (lane & 15)) * BK + kk + (lane >> 4) * 8];
#pragma unroll
            for (int ni = 0; ni < 4; ++ni)
                bfr[ni] = *(const bf16x8*)&u.stg[BM * BK + (wn * 64 + ni * 16 + (lane & 15)) * BK + kk + (lane >> 4) * 8];
#pragma unroll
            for (int mi = 0; mi < 4; ++mi)
#pragma unroll
                for (int ni = 0; ni < 4; ++ni)
                    acc[mi][ni] = __builtin_amdgcn_mfma_f32_16x16x32_bf16(
                        af[mi], bfr[ni], acc[mi][ni], 0, 0, 0);
        }
        __syncthreads();  // LDS reads done before next stage overwrites
    }

    // ---- epilogue: per-neuron MLP over A=4 adjacent z columns ----
    // cell type t is block-uniform: neurons [bx*32, bx*32+32), 256 neurons/type
    const int t = bn0 >> 10;
    float w1[32], b1[8], w2[8];
#pragma unroll
    for (int i = 0; i < 32; ++i) w1[i] = cw1[t * 32 + i];
#pragma unroll
    for (int i = 0; i < 8; ++i) { b1[i] = cb1[t * 8 + i]; w2[i] = cw2[t * 8 + i]; }
    const float b2 = cb2[t];

    // per-wave bias for its 64 columns (col = wn*64 + ni*16 + (lane&15))
    float bcol[4];
#pragma unroll
    for (int ni = 0; ni < 4; ++ni)
        bcol[ni] = bias[bn0 + wn * 64 + ni * 16 + (lane & 15)];

#pragma unroll
    for (int h = 0; h < 2; ++h) {
        // waves owning this 64-row half write z (+bias) to LDS, [m][n] stride ZSTRIDE
        if (wm == h) {
#pragma unroll
            for (int ni = 0; ni < 4; ++ni) {
                const int n = wn * 64 + ni * 16 + (lane & 15);
#pragma unroll
                for (int mi = 0; mi < 4; ++mi) {
                    const int r = mi * 16 + (lane >> 4) * 4;  // row within half
                    f32x4 v = acc[mi][ni];
                    u.z[(r + 0) * ZSTRIDE + n] = v[0] + bcol[ni];
                    u.z[(r + 1) * ZSTRIDE + n] = v[1] + bcol[ni];
                    u.z[(r + 2) * ZSTRIDE + n] = v[2] + bcol[ni];
                    u.z[(r + 3) * ZSTRIDE + n] = v[3] + bcol[ni];
                }
            }
        }
        __syncthreads();

        // 64 rows x 32 neurons = 2048 outputs; 8 per thread.
        // lane->neuron q = i&31 keeps output stores 128B-contiguous.
#pragma unroll
        for (int it = 0; it < 8; ++it) {
            const int i = tid + it * 256;
            const int q = i & 31;       // neuron within block
            const int r = i >> 5;       // row within half
            f32x4 z = *(const f32x4*)&u.z[r * ZSTRIDE + 4 * q];
            float o = 0.f;
#pragma unroll
            for (int hh = 0; hh < 8; ++hh) {
                float pre = z[0] * w1[0 * 8 + hh] + z[1] * w1[1 * 8 + hh]
                          + z[2] * w1[2 * 8 + hh] + z[3] * w1[3 * 8 + hh] + b1[hh];
                float e = __expf(2.0f * pre);
                float th = 1.0f - 2.0f / (e + 1.0f);  // tanh(pre)
                o += th * w2[hh];
            }
            o += b2;
            out[(size_t)(bm0 + h * 64 + r) * 1024 + (bn0 >> 2) + q] = o;
        }
        __syncthreads();  // protect z before other half overwrites
    }
}

extern "C" void kernel_launch(void* const* d_in, const int* in_sizes, int n_in,
                              void* d_out, int out_size, void* d_ws, size_t ws_size,
                              hipStream_t stream) {
    const float* x    = (const float*)d_in[0];
    const float* w    = (const float*)d_in[1];
    const float* bias = (const float*)d_in[2];
    const float* cw1  = (const float*)d_in[3];
    const float* cb1  = (const float*)d_in[4];
    const float* cw2  = (const float*)d_in[5];
    const float* cb2  = (const float*)d_in[6];
    float* out = (float*)d_out;

    __bf16* xb = (__bf16*)d_ws;                       // 8192*1024 bf16 = 16 MB
    __bf16* wb = xb + (size_t)8192 * 1024;            // 4096*1024 bf16 = 8 MB

    const int xn8 = (8192 * 1024) / 8;  // 1048576
    const int wn8 = (4096 * 1024) / 8;  // 524288
    cvt_bf16_kernel<<<xn8 / 256, 256, 0, stream>>>(x, xb, xn8);
    cvt_bf16_kernel<<<wn8 / 256, 256, 0, stream>>>(w, wb, wn8);

    dim3 grid(4096 / BN, 8192 / BM);  // (32, 64)
    fused_gemm_mlp_kernel<<<grid, 256, 0, stream>>>(xb, wb, bias, cw1, cb1, cw2, cb2, out);
}

// Round 2
// 204.009 us; speedup vs baseline: 1.1632x; 1.1632x over previous
//
#include <hip/hip_runtime.h>

// DenseLayerWithComplexNeurons: out = per-cell-type-MLP( x @ W^T + b )
// M = B*S = 8192, K = DIN = 1024, N = A*DOUT = 4096, DOUT = 1024
// T = 4 cell types, G = 256 neurons/type, A = 4, H = 8.
//
// Round 1: bf16 MFMA GEMM (128x128 tile, BK=64, global_load_lds w=16),
//   epilogue fused via LDS round-trip. 154.5 us GEMM, 2.5e7 bank conflicts.
// Round 2: XOR-swizzled staging (kills the 128B-stride bank conflicts on
//   fragment ds_read_b128), hoisted fragment addresses, raw v_exp/v_rcp
//   tanh, single cvt launch.

typedef __bf16 bf16x8 __attribute__((ext_vector_type(8)));
typedef float f32x4 __attribute__((ext_vector_type(4)));

#define BM 128
#define BN 128
#define BK 64
#define KDIM 1024
#define ZSTRIDE 132  // floats; multiple of 4 (16B rows), 132%32=4 -> 2-way max on b32 writes
#define XN8 (8192 * 1024 / 8)
#define WN8 (4096 * 1024 / 8)

__global__ __launch_bounds__(256) void cvt_bf16_kernel(
    const float* __restrict__ x, const float* __restrict__ w,
    __bf16* __restrict__ xb, __bf16* __restrict__ wb) {
    int i = blockIdx.x * 256 + threadIdx.x;
    const float* src;
    __bf16* dst;
    int j;
    if (i < XN8) { src = x; dst = xb; j = i; }
    else         { src = w; dst = wb; j = i - XN8; }
    const f32x4* p = (const f32x4*)src + 2 * (size_t)j;
    f32x4 a = p[0], b = p[1];
    bf16x8 o;
    o[0] = (__bf16)a[0]; o[1] = (__bf16)a[1]; o[2] = (__bf16)a[2]; o[3] = (__bf16)a[3];
    o[4] = (__bf16)b[0]; o[5] = (__bf16)b[1]; o[6] = (__bf16)b[2]; o[7] = (__bf16)b[3];
    ((bf16x8*)dst)[j] = o;
}

union __align__(16) SmemU {
    __bf16 stg[BM * BK + BN * BK];   // A tile then B tile; [row][8 chunks of 16B], chunk XOR row&7
    float  z[64 * ZSTRIDE];          // one 64-row half of the z tile, [m][n] padded
};

__global__ __launch_bounds__(256) void fused_gemm_mlp_kernel(
    const __bf16* __restrict__ Ag,   // [8192][1024] bf16 (x)
    const __bf16* __restrict__ Bg,   // [4096][1024] bf16 (weight, already B^T layout)
    const float* __restrict__ bias,  // [4096]
    const float* __restrict__ cw1,   // [4][4][8]
    const float* __restrict__ cb1,   // [4][8]
    const float* __restrict__ cw2,   // [4][8]
    const float* __restrict__ cb2,   // [4]
    float* __restrict__ out)         // [8192][1024]
{
    __shared__ SmemU u;

    const int tid  = threadIdx.x;
    const int wave = tid >> 6;
    const int lane = tid & 63;
    const int wm = wave >> 1;        // wave row (0..1), 64 rows each
    const int wn = wave & 1;         // wave col (0..1), 64 cols each
    const int bn0 = blockIdx.x * BN; // n offset in [0,4096)
    const int bm0 = blockIdx.y * BM; // m offset in [0,8192)

    f32x4 acc[4][4] = {};

    // ---- staging lane mapping (XOR swizzle) ----
    // within an 8-row chunk: row r = lane>>3; the lane's LDS slot (r, c=lane&7)
    // receives GLOBAL column-chunk (c ^ r). 16B per lane.
    const int srow = lane >> 3;
    const int scol8 = (((lane & 7) ^ srow) * 8);  // element offset of the 16B chunk

    // ---- fragment LDS addresses, hoisted (constant across K-loop) ----
    // data (row R, chunk C) lives at LDS slot (R, C ^ (R&7));
    // R = *+lane&15 so R&7 = lane&7.
    const int lr = lane & 15;
    const int lk = lane >> 4;   // 0..3 -> k-subchunk
    const int lx = lane & 7;
    int aoff[2][4], boff[2][4];
#pragma unroll
    for (int kh = 0; kh < 2; ++kh)
#pragma unroll
        for (int mi = 0; mi < 4; ++mi) {
            const int cidx = kh * 4 + lk;  // column chunk (16B units) within the 128B row
            aoff[kh][mi] = (wm * 64 + mi * 16 + lr) * BK + ((cidx ^ lx) * 8);
            boff[kh][mi] = BM * BK + (wn * 64 + mi * 16 + lr) * BK + ((cidx ^ lx) * 8);
        }

    for (int k0 = 0; k0 < KDIM; k0 += BK) {
        // ---- stage A (128x64) and B (128x64) via global_load_lds width=16 ----
#pragma unroll
        for (int c = 0; c < 4; ++c) {
            const int chunk = wave + c * 4;  // 16 chunks of 8 rows, 4 per wave
            const __bf16* ga = Ag + (size_t)(bm0 + chunk * 8 + srow) * KDIM + k0 + scol8;
            __builtin_amdgcn_global_load_lds(
                (__attribute__((address_space(1))) void*)ga,
                (__attribute__((address_space(3))) void*)&u.stg[chunk * 8 * BK],
                16, 0, 0);
            const __bf16* gb = Bg + (size_t)(bn0 + chunk * 8 + srow) * KDIM + k0 + scol8;
            __builtin_amdgcn_global_load_lds(
                (__attribute__((address_space(1))) void*)gb,
                (__attribute__((address_space(3))) void*)&u.stg[BM * BK + chunk * 8 * BK],
                16, 0, 0);
        }
        __syncthreads();

        // ---- MFMA on the tile: 2 k-halves of 32 ----
#pragma unroll
        for (int kh = 0; kh < 2; ++kh) {
            bf16x8 af[4], bfr[4];
#pragma unroll
            for (int mi = 0; mi < 4; ++mi) af[mi] = *(const bf16x8*)&u.stg[aoff[kh][mi]];
#pragma unroll
            for (int ni = 0; ni < 4; ++ni) bfr[ni] = *(const bf16x8*)&u.stg[boff[kh][ni]];
#pragma unroll
            for (int mi = 0; mi < 4; ++mi)
#pragma unroll
                for (int ni = 0; ni < 4; ++ni)
                    acc[mi][ni] = __builtin_amdgcn_mfma_f32_16x16x32_bf16(
                        af[mi], bfr[ni], acc[mi][ni], 0, 0, 0);
        }
        __syncthreads();
    }

    // ---- epilogue: per-neuron MLP over A=4 adjacent z columns ----
    const int t = bn0 >> 10;  // cell type, block-uniform
    float w1[32], b1[8], w2[8];
#pragma unroll
    for (int i = 0; i < 32; ++i) w1[i] = cw1[t * 32 + i];
#pragma unroll
    for (int i = 0; i < 8; ++i) { b1[i] = cb1[t * 8 + i]; w2[i] = cw2[t * 8 + i]; }
    const float b2 = cb2[t];

    float bcol[4];
#pragma unroll
    for (int ni = 0; ni < 4; ++ni)
        bcol[ni] = bias[bn0 + wn * 64 + ni * 16 + lr];

    const float L2E2 = 2.885390081777927f;  // 2*log2(e)

#pragma unroll
    for (int h = 0; h < 2; ++h) {
        if (wm == h) {
#pragma unroll
            for (int ni = 0; ni < 4; ++ni) {
                const int n = wn * 64 + ni * 16 + lr;
#pragma unroll
                for (int mi = 0; mi < 4; ++mi) {
                    const int r = mi * 16 + lk * 4;  // row within half
                    f32x4 v = acc[mi][ni];
                    u.z[(r + 0) * ZSTRIDE + n] = v[0] + bcol[ni];
                    u.z[(r + 1) * ZSTRIDE + n] = v[1] + bcol[ni];
                    u.z[(r + 2) * ZSTRIDE + n] = v[2] + bcol[ni];
                    u.z[(r + 3) * ZSTRIDE + n] = v[3] + bcol[ni];
                }
            }
        }
        __syncthreads();

        // 64 rows x 32 neurons = 2048 outputs; 8 per thread.
#pragma unroll
        for (int it = 0; it < 8; ++it) {
            const int i = tid + it * 256;
            const int q = i & 31;       // neuron within block
            const int r = i >> 5;       // row within half
            f32x4 z = *(const f32x4*)&u.z[r * ZSTRIDE + 4 * q];
            float o = 0.f;
#pragma unroll
            for (int hh = 0; hh < 8; ++hh) {
                float pre = z[0] * w1[0 * 8 + hh] + z[1] * w1[1 * 8 + hh]
                          + z[2] * w1[2 * 8 + hh] + z[3] * w1[3 * 8 + hh] + b1[hh];
                float e = __builtin_amdgcn_exp2f(pre * L2E2);        // e^(2*pre)
                float th = 1.0f - 2.0f * __builtin_amdgcn_rcpf(e + 1.0f);
                o += th * w2[hh];
            }
            o += b2;
            out[(size_t)(bm0 + h * 64 + r) * 1024 + (bn0 >> 2) + q] = o;
        }
        __syncthreads();
    }
}

extern "C" void kernel_launch(void* const* d_in, const int* in_sizes, int n_in,
                              void* d_out, int out_size, void* d_ws, size_t ws_size,
                              hipStream_t stream) {
    const float* x    = (const float*)d_in[0];
    const float* w    = (const float*)d_in[1];
    const float* bias = (const float*)d_in[2];
    const float* cw1  = (const float*)d_in[3];
    const float* cb1  = (const float*)d_in[4];
    const float* cw2  = (const float*)d_in[5];
    const float* cb2  = (const float*)d_in[6];
    float* out = (float*)d_out;

    __bf16* xb = (__bf16*)d_ws;                       // 8192*1024 bf16 = 16 MB
    __bf16* wb = xb + (size_t)8192 * 1024;            // 4096*1024 bf16 = 8 MB

    cvt_bf16_kernel<<<(XN8 + WN8) / 256, 256, 0, stream>>>(x, w, xb, wb);

    dim3 grid(4096 / BN, 8192 / BM);  // (32, 64)
    fused_gemm_mlp_kernel<<<grid, 256, 0, stream>>>(xb, wb, bias, cw1, cb1, cw2, cb2, out);
}

// Round 3
// 188.052 us; speedup vs baseline: 1.2619x; 1.0849x over previous
//
#include <hip/hip_runtime.h>

// DenseLayerWithComplexNeurons: out = per-cell-type-MLP( x @ W^T + b )
// M = B*S = 8192, K = DIN = 1024, N = A*DOUT = 4096, DOUT = 1024
// T = 4 cell types, G = 256 neurons/type, A = 4, H = 8.
//
// Round 1: bf16 MFMA GEMM 128x128/BK64, fused LDS epilogue. 154.5 us, 2.5e7 conflicts.
// Round 2: XOR-swizzled staging -> 0 conflicts, 118.9 us. LDS-BW-bound (64x64
//   wave tile = 32.8 FLOP/LDS-byte; LDS pipe ~55 us vs MFMA 33 us).
// Round 3: 256x128 block, 128x64 wave tiles, 32x32x16 MFMA (2495 TF ubench,
//   25% fewer ds_read/FLOP, half the barriers/FLOP). Same swizzle; epilogue
//   in 4 half-tiles of 64 rows.

typedef __bf16 bf16x8 __attribute__((ext_vector_type(8)));
typedef float f32x4 __attribute__((ext_vector_type(4)));
typedef float f32x16 __attribute__((ext_vector_type(16)));

#define BM 256
#define BN 128
#define BK 64
#define KDIM 1024
#define A_ELEMS (BM * BK)            // 16384 bf16 = 32 KB
#define ZSTRIDE 132                  // floats; 132%32=4 keeps b32 write halves conflict-free
#define XN8 (8192 * 1024 / 8)
#define WN8 (4096 * 1024 / 8)

__global__ __launch_bounds__(256) void cvt_bf16_kernel(
    const float* __restrict__ x, const float* __restrict__ w,
    __bf16* __restrict__ xb, __bf16* __restrict__ wb) {
    int i = blockIdx.x * 256 + threadIdx.x;
    const float* src;
    __bf16* dst;
    int j;
    if (i < XN8) { src = x; dst = xb; j = i; }
    else         { src = w; dst = wb; j = i - XN8; }
    const f32x4* p = (const f32x4*)src + 2 * (size_t)j;
    f32x4 a = p[0], b = p[1];
    bf16x8 o;
    o[0] = (__bf16)a[0]; o[1] = (__bf16)a[1]; o[2] = (__bf16)a[2]; o[3] = (__bf16)a[3];
    o[4] = (__bf16)b[0]; o[5] = (__bf16)b[1]; o[6] = (__bf16)b[2]; o[7] = (__bf16)b[3];
    ((bf16x8*)dst)[j] = o;
}

union __align__(16) SmemU {
    __bf16 stg[A_ELEMS + BN * BK];   // A tile (256x64) then B tile (128x64); 16B chunk c stored at c^(row&7)
    float  z[64 * ZSTRIDE];          // one 64-row slab of the z tile, [m][n] padded
};

__global__ __launch_bounds__(256, 2) void fused_gemm_mlp_kernel(
    const __bf16* __restrict__ Ag,   // [8192][1024] bf16 (x)
    const __bf16* __restrict__ Bg,   // [4096][1024] bf16 (weight, already B^T layout)
    const float* __restrict__ bias,  // [4096]
    const float* __restrict__ cw1,   // [4][4][8]
    const float* __restrict__ cb1,   // [4][8]
    const float* __restrict__ cw2,   // [4][8]
    const float* __restrict__ cb2,   // [4]
    float* __restrict__ out)         // [8192][1024]
{
    __shared__ SmemU u;

    const int tid  = threadIdx.x;
    const int wave = tid >> 6;
    const int lane = tid & 63;
    const int wm = wave >> 1;        // row half (0..1): 128 rows each
    const int wn = wave & 1;         // col half (0..1): 64 cols each
    const int bn0 = blockIdx.x * BN; // n offset in [0,4096)
    const int bm0 = blockIdx.y * BM; // m offset in [0,8192)

    f32x16 acc[4][2] = {};           // 4 m-tiles x 2 n-tiles of 32x32

    // ---- staging lane mapping (XOR swizzle, per 8-row chunk) ----
    const int srow  = lane >> 3;
    const int scol8 = (((lane & 7) ^ srow) * 8);

    // ---- fragment LDS base addresses per k-step (hoisted) ----
    // A-frag 32x32x16: row = lane&31, k = (lane>>5)*8 + i  (B mirrors with col)
    const int lr5 = lane & 31;
    const int lk2 = lane >> 5;   // 0..1
    const int lx  = lane & 7;
    int a_base[4], b_base[4];
#pragma unroll
    for (int kh = 0; kh < 4; ++kh) {
        const int cx = ((kh * 2 + lk2) ^ lx) * 16;  // swizzled 16B chunk byte offset
        a_base[kh] = (wm * 128 + lr5) * (BK * 2) + cx;
        b_base[kh] = A_ELEMS * 2 + (wn * 64 + lr5) * (BK * 2) + cx;
    }
    const char* sb = (const char*)u.stg;

    for (int k0 = 0; k0 < KDIM; k0 += BK) {
        // ---- stage A (256x64) + B (128x64) via global_load_lds width=16 ----
#pragma unroll
        for (int c = 0; c < 8; ++c) {  // A: 32 chunks of 8 rows, 8 per wave
            const int chunk = wave + c * 4;
            const __bf16* ga = Ag + (size_t)(bm0 + chunk * 8 + srow) * KDIM + k0 + scol8;
            __builtin_amdgcn_global_load_lds(
                (__attribute__((address_space(1))) void*)ga,
                (__attribute__((address_space(3))) void*)&u.stg[chunk * 8 * BK],
                16, 0, 0);
        }
#pragma unroll
        for (int c = 0; c < 4; ++c) {  // B: 16 chunks of 8 rows, 4 per wave
            const int chunk = wave + c * 4;
            const __bf16* gb = Bg + (size_t)(bn0 + chunk * 8 + srow) * KDIM + k0 + scol8;
            __builtin_amdgcn_global_load_lds(
                (__attribute__((address_space(1))) void*)gb,
                (__attribute__((address_space(3))) void*)&u.stg[A_ELEMS + chunk * 8 * BK],
                16, 0, 0);
        }
        __syncthreads();

        // ---- MFMA: 4 k-steps of 16 ----
#pragma unroll
        for (int kh = 0; kh < 4; ++kh) {
            bf16x8 af[4], bfr[2];
#pragma unroll
            for (int mi = 0; mi < 4; ++mi)
                af[mi] = *(const bf16x8*)(sb + a_base[kh] + mi * 4096);
#pragma unroll
            for (int ni = 0; ni < 2; ++ni)
                bfr[ni] = *(const bf16x8*)(sb + b_base[kh] + ni * 4096);
#pragma unroll
            for (int mi = 0; mi < 4; ++mi)
#pragma unroll
                for (int ni = 0; ni < 2; ++ni)
                    acc[mi][ni] = __builtin_amdgcn_mfma_f32_32x32x16_bf16(
                        af[mi], bfr[ni], acc[mi][ni], 0, 0, 0);
        }
        __syncthreads();
    }

    // ---- epilogue: per-neuron MLP over A=4 adjacent z columns ----
    const int t = bn0 >> 10;  // cell type, block-uniform
    float w1[32], b1[8], w2[8];
#pragma unroll
    for (int i = 0; i < 32; ++i) w1[i] = cw1[t * 32 + i];
#pragma unroll
    for (int i = 0; i < 8; ++i) { b1[i] = cb1[t * 8 + i]; w2[i] = cw2[t * 8 + i]; }
    const float b2 = cb2[t];

    float bcol[2];
#pragma unroll
    for (int ni = 0; ni < 2; ++ni)
        bcol[ni] = bias[bn0 + wn * 64 + ni * 32 + lr5];

    const float L2E2 = 2.885390081777927f;  // 2*log2(e)

#pragma unroll
    for (int h = 0; h < 4; ++h) {  // 64-row slabs
        if (wm == (h >> 1)) {
            const int mi0 = (h & 1) * 2;
#pragma unroll
            for (int dmi = 0; dmi < 2; ++dmi) {
                const int mi = mi0 + dmi;
#pragma unroll
                for (int ni = 0; ni < 2; ++ni) {
                    const int n = wn * 64 + ni * 32 + lr5;
#pragma unroll
                    for (int g = 0; g < 4; ++g) {
                        // C/D 32x32 layout: col=lane&31, row=(reg&3)+8*(reg>>2)+4*(lane>>5)
                        const int rb = dmi * 32 + g * 8 + lk2 * 4;
                        u.z[(rb + 0) * ZSTRIDE + n] = acc[mi][ni][g * 4 + 0] + bcol[ni];
                        u.z[(rb + 1) * ZSTRIDE + n] = acc[mi][ni][g * 4 + 1] + bcol[ni];
                        u.z[(rb + 2) * ZSTRIDE + n] = acc[mi][ni][g * 4 + 2] + bcol[ni];
                        u.z[(rb + 3) * ZSTRIDE + n] = acc[mi][ni][g * 4 + 3] + bcol[ni];
                    }
                }
            }
        }
        __syncthreads();

        // 64 rows x 32 neurons = 2048 outputs; 8 per thread
#pragma unroll
        for (int it = 0; it < 8; ++it) {
            const int i = tid + it * 256;
            const int q = i & 31;       // neuron within block
            const int r = i >> 5;       // row within slab
            f32x4 z = *(const f32x4*)&u.z[r * ZSTRIDE + 4 * q];
            float o = 0.f;
#pragma unroll
            for (int hh = 0; hh < 8; ++hh) {
                float pre = z[0] * w1[0 * 8 + hh] + z[1] * w1[1 * 8 + hh]
                          + z[2] * w1[2 * 8 + hh] + z[3] * w1[3 * 8 + hh] + b1[hh];
                float e = __builtin_amdgcn_exp2f(pre * L2E2);        // e^(2*pre)
                float th = 1.0f - 2.0f * __builtin_amdgcn_rcpf(e + 1.0f);
                o += th * w2[hh];
            }
            o += b2;
            out[(size_t)(bm0 + h * 64 + r) * 1024 + (bn0 >> 2) + q] = o;
        }
        __syncthreads();
    }
}

extern "C" void kernel_launch(void* const* d_in, const int* in_sizes, int n_in,
                              void* d_out, int out_size, void* d_ws, size_t ws_size,
                              hipStream_t stream) {
    const float* x    = (const float*)d_in[0];
    const float* w    = (const float*)d_in[1];
    const float* bias = (const float*)d_in[2];
    const float* cw1  = (const float*)d_in[3];
    const float* cb1  = (const float*)d_in[4];
    const float* cw2  = (const float*)d_in[5];
    const float* cb2  = (const float*)d_in[6];
    float* out = (float*)d_out;

    __bf16* xb = (__bf16*)d_ws;                       // 8192*1024 bf16 = 16 MB
    __bf16* wb = xb + (size_t)8192 * 1024;            // 4096*1024 bf16 = 8 MB

    cvt_bf16_kernel<<<(XN8 + WN8) / 256, 256, 0, stream>>>(x, w, xb, wb);

    dim3 grid(4096 / BN, 8192 / BM);  // (32, 32)
    fused_gemm_mlp_kernel<<<grid, 256, 0, stream>>>(xb, wb, bias, cw1, cb1, cw2, cb2, out);
}